// Round 13
// baseline (5586.646 us; speedup 1.0000x reference)
//
#include <hip/hip_runtime.h>
#include <hip/hip_bf16.h>

typedef unsigned short u16;
typedef unsigned int u32;
typedef __attribute__((ext_vector_type(8))) short short8v;      // MFMA bf16 frag (4 VGPR)
typedef __attribute__((ext_vector_type(8))) unsigned short ushort8v;
typedef __attribute__((ext_vector_type(4))) float float4v;
typedef __attribute__((ext_vector_type(4))) unsigned int uint4v;

#define S_LEN 1024
#define BATCH 256
#define VOCAB 32000
#define EMBED 512
#define HIDDEN 1024
#define BH (BATCH * HIDDEN)
#define MB_SLOT 1048576   // bytes per mailbox slot: 16g x 4w x 64lane x 16unit x 16B

__device__ inline u16 f2bf(float f) {
  return __builtin_bit_cast(u16, __float2bfloat16(f));  // RNE
}

// Coherent write-through 16B store (sc0|sc1 = cpol 17 -> L3 coherent point).
__device__ inline void cohstore16u(u16* base, int voff, uint4v v) {
  __amdgpu_buffer_rsrc_t r =
      __builtin_amdgcn_make_buffer_rsrc((void*)base, (short)0, -1, 0x00020000);
  __builtin_amdgcn_raw_buffer_store_b128(v, r, voff, 0, 17);
}

__device__ inline short8v cvt8(float4v a, float4v b) {
  ushort8v v;
  v[0]=f2bf(a[0]); v[1]=f2bf(a[1]); v[2]=f2bf(a[2]); v[3]=f2bf(a[3]);
  v[4]=f2bf(b[0]); v[5]=f2bf(b[1]); v[6]=f2bf(b[2]); v[7]=f2bf(b[3]);
  return __builtin_bit_cast(short8v, v);
}

__device__ inline short8v mkfrag(uint4v A, uint4v B) {
  uint4v f = {A[1], A[2], B[1], B[2]};
  return __builtin_bit_cast(short8v, f);
}

// ---------------- prep: zero mailbox (2MB); emb -> bf16 ----------------
__global__ __launch_bounds__(256) void prep_kernel(u16* __restrict__ mbx,
                                                   const float* __restrict__ emb,
                                                   u16* __restrict__ emb16,
                                                   int do_emb) {
  int i = blockIdx.x * 256 + threadIdx.x;
  const int NZ = (2 * MB_SLOT) / 16;    // 131072
  if (i < NZ) {
    ushort8v z = {0,0,0,0,0,0,0,0};
    *(ushort8v*)(mbx + (size_t)i * 8) = z;
  } else if (do_emb) {
    int j = i - NZ;
    if (j < (VOCAB * EMBED) / 8) {
      const float* s = emb + (size_t)j * 8;
      *(ushort8v*)(emb16 + (size_t)j * 8) = __builtin_bit_cast(
          ushort8v, cvt8(*(const float4v*)s, *(const float4v*)(s + 4)));
    }
  }
}

// ---------------- fused recurrence + input projection ----------------
// 256 persistent blocks = 16 groups x 16 col-tiles. Weights in VGPR.
// Exchange: TAG-CARRIED DATA. Unit = 16B {u32 tag=t+1, 4 bf16, pad} written
// by ONE dwordx4 (single transaction). Producer: 1 unit/thread, fire&forget
// (no drain, no flag). Consumer: poll its 16 units (asm: 16 loads + vmcnt(0));
// all tags==t => data already in regs. Anti-overwrite invariant preserved by
// the block-wide reduce barrier (same as R10's proof).
__global__ __launch_bounds__(256, 1) void rnn_fused(const int* __restrict__ xseq,
                                                    const float* __restrict__ emb,
                                                    const float* __restrict__ wih,
                                                    const float* __restrict__ bih,
                                                    const float* __restrict__ whh,
                                                    const float* __restrict__ bhh,
                                                    u16* __restrict__ mbx,
                                                    float* __restrict__ out,
                                                    const u16* __restrict__ emb16,
                                                    int eb16) {
  extern __shared__ u16 smem[];
  u16* xq = smem;                                   // [1024][16] token ids, 32KB
  float (*red)[4][16][68] = (float (*)[4][16][68])(smem + S_LEN * 16);  // 34KB
  const int tid = threadIdx.x;
  const int lane = tid & 63, w = tid >> 6;
  const int l15 = lane & 15, l4 = lane >> 4;
  const int g = blockIdx.x & 15;
  const int jt = blockIdx.x >> 4;

  // ---- prologue: weights into registers ----
  short8v Wf[4][8];
  #pragma unroll
  for (int jj = 0; jj < 4; jj++)
    #pragma unroll
    for (int kq = 0; kq < 8; kq++) {
      const float* s = whh + (size_t)(jt * 64 + jj * 16 + l15) * HIDDEN
                       + w * 256 + kq * 32 + l4 * 8;
      Wf[jj][kq] = cvt8(*(const float4v*)s, *(const float4v*)(s + 4));
    }
  short8v Wihf[4][4];
  #pragma unroll
  for (int jj = 0; jj < 4; jj++)
    #pragma unroll
    for (int kk = 0; kk < 4; kk++) {
      const float* s = wih + (size_t)(jt * 64 + jj * 16 + l15) * EMBED
                       + w * 128 + kk * 32 + l4 * 8;
      Wihf[jj][kk] = cvt8(*(const float4v*)s, *(const float4v*)(s + 4));
    }
  for (int i = tid; i < S_LEN * 16; i += 256)
    xq[i] = (u16)xseq[(i >> 4) * BATCH + g * 16 + (i & 15)];
  // producer tail ownership (all 256 threads): row trow, cols tc4..tc4+4
  const int trow = w * 4 + (lane >> 4);
  const int tc4 = (lane & 15) * 4;
  float bsum[4];
  #pragma unroll
  for (int i = 0; i < 4; i++)
    bsum[i] = bhh[jt * 64 + tc4 + i] + bih[jt * 64 + tc4 + i];
  // producer mailbox slot for this thread's unit (byte offset within slot)
  const int w_t = jt >> 2;
  const int l_t = trow + 16 * ((tc4 >> 3) & 3);
  const int u_idx = (jt & 3) * 4 + ((tc4 >> 5) & 1) * 2 + ((tc4 >> 2) & 1);
  const int moff = (((g * 4 + w_t) * 64 + l_t) * 16 + u_idx) * 16;
  // consumer poll base (u16 units within slot)
  const int cbase = ((g * 4 + w) * 64 + lane) * 128;
  __syncthreads();  // xq ready

  // ---- xp-partials for t=0 ----
  float4v xacc[4] = {};
  if (eb16) {
    const u16* er0 = emb16 + (size_t)xq[l15] * EMBED + w * 128 + l4 * 8;
    #pragma unroll
    for (int kk = 0; kk < 4; kk++) {
      short8v af = *(const short8v*)(er0 + kk * 32);
      #pragma unroll
      for (int jj = 0; jj < 4; jj++)
        xacc[jj] = __builtin_amdgcn_mfma_f32_16x16x32_bf16(af, Wihf[jj][kk], xacc[jj], 0, 0, 0);
    }
  } else {
    const float* er0 = emb + (size_t)xq[l15] * EMBED + w * 128 + l4 * 8;
    #pragma unroll
    for (int kk = 0; kk < 4; kk++) {
      short8v af = cvt8(*(const float4v*)(er0 + kk * 32),
                        *(const float4v*)(er0 + kk * 32 + 4));
      #pragma unroll
      for (int jj = 0; jj < 4; jj++)
        xacc[jj] = __builtin_amdgcn_mfma_f32_16x16x32_bf16(af, Wihf[jj][kk], xacc[jj], 0, 0, 0);
    }
  }

  for (int t = 0; t < S_LEN; t++) {
    float* outt = out + (size_t)t * BH;
    float4v accp[4] = {xacc[0], xacc[1], xacc[2], xacc[3]};
    // e-loads for t+1 (plain cached; land by the poll's vmcnt(0))
    int tn = (t + 1 < S_LEN) ? (t + 1) : t;
    short8v ebf[4];
    float4v e[8];
    if (eb16) {
      const u16* er = emb16 + (size_t)xq[tn * 16 + l15] * EMBED + w * 128 + l4 * 8;
      #pragma unroll
      for (int kk = 0; kk < 4; kk++)
        ebf[kk] = *(const short8v*)(er + kk * 32);
    } else {
      const float* er = emb + (size_t)xq[tn * 16 + l15] * EMBED + w * 128 + l4 * 8;
      #pragma unroll
      for (int kk = 0; kk < 4; kk++) {
        e[2 * kk]     = *(const float4v*)(er + kk * 32);
        e[2 * kk + 1] = *(const float4v*)(er + kk * 32 + 4);
      }
    }
    if (t > 0) {
      // poll own 16 units of slot[t&1]; tags==t imply data valid (same 16B txn)
      const u16* pb = mbx + (size_t)(t & 1) * (MB_SLOT / 2) + cbase;
      uint4v u0,u1,u2,u3,u4,u5,u6,u7,u8,u9,u10,u11,u12,u13,u14,u15;
      const u32 tt = (u32)t;
      bool ok;
      do {
        asm volatile(
          "global_load_dwordx4 %0, %16, off sc0 sc1\n\t"
          "global_load_dwordx4 %1, %16, off offset:16 sc0 sc1\n\t"
          "global_load_dwordx4 %2, %16, off offset:32 sc0 sc1\n\t"
          "global_load_dwordx4 %3, %16, off offset:48 sc0 sc1\n\t"
          "global_load_dwordx4 %4, %16, off offset:64 sc0 sc1\n\t"
          "global_load_dwordx4 %5, %16, off offset:80 sc0 sc1\n\t"
          "global_load_dwordx4 %6, %16, off offset:96 sc0 sc1\n\t"
          "global_load_dwordx4 %7, %16, off offset:112 sc0 sc1\n\t"
          "global_load_dwordx4 %8, %16, off offset:128 sc0 sc1\n\t"
          "global_load_dwordx4 %9, %16, off offset:144 sc0 sc1\n\t"
          "global_load_dwordx4 %10, %16, off offset:160 sc0 sc1\n\t"
          "global_load_dwordx4 %11, %16, off offset:176 sc0 sc1\n\t"
          "global_load_dwordx4 %12, %16, off offset:192 sc0 sc1\n\t"
          "global_load_dwordx4 %13, %16, off offset:208 sc0 sc1\n\t"
          "global_load_dwordx4 %14, %16, off offset:224 sc0 sc1\n\t"
          "global_load_dwordx4 %15, %16, off offset:240 sc0 sc1\n\t"
          "s_waitcnt vmcnt(0)"
          : "=&v"(u0), "=&v"(u1), "=&v"(u2), "=&v"(u3),
            "=&v"(u4), "=&v"(u5), "=&v"(u6), "=&v"(u7),
            "=&v"(u8), "=&v"(u9), "=&v"(u10), "=&v"(u11),
            "=&v"(u12), "=&v"(u13), "=&v"(u14), "=&v"(u15)
          : "v"(pb) : "memory");
        ok = (u0[0]==tt) & (u1[0]==tt) & (u2[0]==tt) & (u3[0]==tt) &
             (u4[0]==tt) & (u5[0]==tt) & (u6[0]==tt) & (u7[0]==tt) &
             (u8[0]==tt) & (u9[0]==tt) & (u10[0]==tt) & (u11[0]==tt) &
             (u12[0]==tt) & (u13[0]==tt) & (u14[0]==tt) & (u15[0]==tt);
      } while (!ok);
      // repack: frag kq = units 2kq, 2kq+1
      short8v afr[8];
      afr[0] = mkfrag(u0, u1);   afr[1] = mkfrag(u2, u3);
      afr[2] = mkfrag(u4, u5);   afr[3] = mkfrag(u6, u7);
      afr[4] = mkfrag(u8, u9);   afr[5] = mkfrag(u10, u11);
      afr[6] = mkfrag(u12, u13); afr[7] = mkfrag(u14, u15);
      #pragma unroll
      for (int kq = 0; kq < 8; kq++)
        #pragma unroll
        for (int jj = 0; jj < 4; jj++)
          accp[jj] = __builtin_amdgcn_mfma_f32_16x16x32_bf16(afr[kq], Wf[jj][kq], accp[jj], 0, 0, 0);
    }
    // partials -> red[t&1]; ONE barrier (also orders polls before stores)
    const int p = t & 1;
    #pragma unroll
    for (int jj = 0; jj < 4; jj++)
      #pragma unroll
      for (int q = 0; q < 4; q++)
        red[p][w][l4 * 4 + q][jj * 16 + l15] = accp[jj][q];
    __syncthreads();
    float4v r0 = *(const float4v*)&red[p][0][trow][tc4];
    float4v r1 = *(const float4v*)&red[p][1][trow][tc4];
    float4v r2 = *(const float4v*)&red[p][2][trow][tc4];
    float4v r3 = *(const float4v*)&red[p][3][trow][tc4];
    float th[4];
    #pragma unroll
    for (int i = 0; i < 4; i++) {
      float s = r0[i] + r1[i] + r2[i] + r3[i] + bsum[i];
      float ex = __expf(-2.0f * fabsf(s));
      float v = (1.0f - ex) / (1.0f + ex);
      th[i] = copysignf(v, s);
    }
    // mailbox unit store: {tag t+1, 4 bf16, pad} -> slot[(t+1)&1]; fire&forget
    uint4v mval;
    mval[0] = (u32)(t + 1);
    mval[1] = (u32)f2bf(th[0]) | ((u32)f2bf(th[1]) << 16);
    mval[2] = (u32)f2bf(th[2]) | ((u32)f2bf(th[3]) << 16);
    mval[3] = 0u;
    cohstore16u(mbx, ((t + 1) & 1) * MB_SLOT + moff, mval);
    // fp32 out store (nobody reads it cross-block)
    float4v o = {th[0], th[1], th[2], th[3]};
    *(float4v*)(outt + (size_t)(g * 16 + trow) * HIDDEN + jt * 64 + tc4) = o;
    // xp-MFMA for t+1 (overlaps next poll wait)
    float4v xn[4] = {};
    #pragma unroll
    for (int kk = 0; kk < 4; kk++) {
      short8v af = eb16 ? ebf[kk] : cvt8(e[2 * kk], e[2 * kk + 1]);
      #pragma unroll
      for (int jj = 0; jj < 4; jj++)
        xn[jj] = __builtin_amdgcn_mfma_f32_16x16x32_bf16(af, Wihf[jj][kk], xn[jj], 0, 0, 0);
    }
    xacc[0] = xn[0]; xacc[1] = xn[1]; xacc[2] = xn[2]; xacc[3] = xn[3];
  }
}

extern "C" void kernel_launch(void* const* d_in, const int* in_sizes, int n_in,
                              void* d_out, int out_size, void* d_ws, size_t ws_size,
                              hipStream_t stream) {
  const int* xseq   = (const int*)d_in[0];
  const float* emb  = (const float*)d_in[1];
  const float* wih  = (const float*)d_in[2];
  const float* bih  = (const float*)d_in[3];
  const float* whh  = (const float*)d_in[4];
  const float* bhh  = (const float*)d_in[5];
  float* out = (float*)d_out;
  char* ws = (char*)d_ws;
  u16* mbx   = (u16*)ws;                      // 2,097,152 B (2 mailbox slots)
  u16* emb16 = (u16*)(ws + 2097152);          // 32,768,000 B (bf16 emb)

  const size_t need = 2097152u + (size_t)VOCAB * EMBED * 2u;
  const int do_emb = (ws_size >= need) ? 1 : 0;
  const int prep_items = 131072 + (do_emb ? (VOCAB * EMBED) / 8 : 0);

  prep_kernel<<<(prep_items + 255) / 256, 256, 0, stream>>>(mbx, emb, emb16, do_emb);
  (void)hipFuncSetAttribute((const void*)rnn_fused,
                            hipFuncAttributeMaxDynamicSharedMemorySize, 67584);
  rnn_fused<<<256, 256, 67584, stream>>>(xseq, emb, wih, bih, whh, bhh,
                                         mbx, out, emb16, do_emb);
}

// Round 14
// 5561.490 us; speedup vs baseline: 1.0045x; 1.0045x over previous
//
#include <hip/hip_runtime.h>
#include <hip/hip_bf16.h>

typedef unsigned short u16;
typedef unsigned int u32;
typedef __attribute__((ext_vector_type(8))) short short8v;      // MFMA bf16 frag (4 VGPR)
typedef __attribute__((ext_vector_type(8))) unsigned short ushort8v;
typedef __attribute__((ext_vector_type(4))) float float4v;
typedef __attribute__((ext_vector_type(4))) unsigned int uint4v;

#define S_LEN 1024
#define BATCH 256
#define VOCAB 32000
#define EMBED 512
#define HIDDEN 1024
#define BH (BATCH * HIDDEN)
#define MB_SLOT 1048576   // bytes per mailbox slot

__device__ inline u16 f2bf(float f) {
  return __builtin_bit_cast(u16, __float2bfloat16(f));  // RNE
}

// Coherent write-through 16B store (sc0|sc1 = cpol 17 -> L3 coherent point).
__device__ inline void cohstore16u(u16* base, int voff, uint4v v) {
  __amdgpu_buffer_rsrc_t r =
      __builtin_amdgcn_make_buffer_rsrc((void*)base, (short)0, -1, 0x00020000);
  __builtin_amdgcn_raw_buffer_store_b128(v, r, voff, 0, 17);
}

__device__ inline short8v cvt8(float4v a, float4v b) {
  ushort8v v;
  v[0]=f2bf(a[0]); v[1]=f2bf(a[1]); v[2]=f2bf(a[2]); v[3]=f2bf(a[3]);
  v[4]=f2bf(b[0]); v[5]=f2bf(b[1]); v[6]=f2bf(b[2]); v[7]=f2bf(b[3]);
  return __builtin_bit_cast(short8v, v);
}

__device__ inline short8v mkfrag(uint4v A, uint4v B) {
  uint4v f = {A[1], A[2], B[1], B[2]};
  return __builtin_bit_cast(short8v, f);
}

// Full 16-unit (16B each) coherent load of this thread's mailbox span.
#define LOAD_UNITS(pb) \
  asm volatile( \
    "global_load_dwordx4 %0, %16, off sc0 sc1\n\t" \
    "global_load_dwordx4 %1, %16, off offset:16 sc0 sc1\n\t" \
    "global_load_dwordx4 %2, %16, off offset:32 sc0 sc1\n\t" \
    "global_load_dwordx4 %3, %16, off offset:48 sc0 sc1\n\t" \
    "global_load_dwordx4 %4, %16, off offset:64 sc0 sc1\n\t" \
    "global_load_dwordx4 %5, %16, off offset:80 sc0 sc1\n\t" \
    "global_load_dwordx4 %6, %16, off offset:96 sc0 sc1\n\t" \
    "global_load_dwordx4 %7, %16, off offset:112 sc0 sc1\n\t" \
    "global_load_dwordx4 %8, %16, off offset:128 sc0 sc1\n\t" \
    "global_load_dwordx4 %9, %16, off offset:144 sc0 sc1\n\t" \
    "global_load_dwordx4 %10, %16, off offset:160 sc0 sc1\n\t" \
    "global_load_dwordx4 %11, %16, off offset:176 sc0 sc1\n\t" \
    "global_load_dwordx4 %12, %16, off offset:192 sc0 sc1\n\t" \
    "global_load_dwordx4 %13, %16, off offset:208 sc0 sc1\n\t" \
    "global_load_dwordx4 %14, %16, off offset:224 sc0 sc1\n\t" \
    "global_load_dwordx4 %15, %16, off offset:240 sc0 sc1\n\t" \
    "s_waitcnt vmcnt(0)" \
    : "=&v"(u0), "=&v"(u1), "=&v"(u2), "=&v"(u3), \
      "=&v"(u4), "=&v"(u5), "=&v"(u6), "=&v"(u7), \
      "=&v"(u8), "=&v"(u9), "=&v"(u10), "=&v"(u11), \
      "=&v"(u12), "=&v"(u13), "=&v"(u14), "=&v"(u15) \
    : "v"(pb) : "memory")

// Cheap tag-only load (16 x dword = 64B/lane).
#define LOAD_TAGS(pb) \
  asm volatile( \
    "global_load_dword %0, %16, off sc0 sc1\n\t" \
    "global_load_dword %1, %16, off offset:16 sc0 sc1\n\t" \
    "global_load_dword %2, %16, off offset:32 sc0 sc1\n\t" \
    "global_load_dword %3, %16, off offset:48 sc0 sc1\n\t" \
    "global_load_dword %4, %16, off offset:64 sc0 sc1\n\t" \
    "global_load_dword %5, %16, off offset:80 sc0 sc1\n\t" \
    "global_load_dword %6, %16, off offset:96 sc0 sc1\n\t" \
    "global_load_dword %7, %16, off offset:112 sc0 sc1\n\t" \
    "global_load_dword %8, %16, off offset:128 sc0 sc1\n\t" \
    "global_load_dword %9, %16, off offset:144 sc0 sc1\n\t" \
    "global_load_dword %10, %16, off offset:160 sc0 sc1\n\t" \
    "global_load_dword %11, %16, off offset:176 sc0 sc1\n\t" \
    "global_load_dword %12, %16, off offset:192 sc0 sc1\n\t" \
    "global_load_dword %13, %16, off offset:208 sc0 sc1\n\t" \
    "global_load_dword %14, %16, off offset:224 sc0 sc1\n\t" \
    "global_load_dword %15, %16, off offset:240 sc0 sc1\n\t" \
    "s_waitcnt vmcnt(0)" \
    : "=&v"(g0), "=&v"(g1), "=&v"(g2), "=&v"(g3), \
      "=&v"(g4), "=&v"(g5), "=&v"(g6), "=&v"(g7), \
      "=&v"(g8), "=&v"(g9), "=&v"(g10), "=&v"(g11), \
      "=&v"(g12), "=&v"(g13), "=&v"(g14), "=&v"(g15) \
    : "v"(pb) : "memory")

// ---------------- prep: zero mailbox (2MB); emb -> bf16 ----------------
__global__ __launch_bounds__(256) void prep_kernel(u16* __restrict__ mbx,
                                                   const float* __restrict__ emb,
                                                   u16* __restrict__ emb16,
                                                   int do_emb) {
  int i = blockIdx.x * 256 + threadIdx.x;
  const int NZ = (2 * MB_SLOT) / 16;    // 131072
  if (i < NZ) {
    ushort8v z = {0,0,0,0,0,0,0,0};
    *(ushort8v*)(mbx + (size_t)i * 8) = z;
  } else if (do_emb) {
    int j = i - NZ;
    if (j < (VOCAB * EMBED) / 8) {
      const float* s = emb + (size_t)j * 8;
      *(ushort8v*)(emb16 + (size_t)j * 8) = __builtin_bit_cast(
          ushort8v, cvt8(*(const float4v*)s, *(const float4v*)(s + 4)));
    }
  }
}

// ---------------- fused recurrence + input projection ----------------
// 256 persistent blocks = 16 groups x 16 col-tiles. Weights in VGPR.
// Exchange: tag-carried 16B units (PROVEN R13), fire&forget producer (no
// drain, no flag). Consumer: SPECULATIVE full load first (tags fresh => data
// already in regs, zero extra RTT); fallback = cheap tag-only spin + reload.
__global__ __launch_bounds__(256, 1) void rnn_fused(const int* __restrict__ xseq,
                                                    const float* __restrict__ emb,
                                                    const float* __restrict__ wih,
                                                    const float* __restrict__ bih,
                                                    const float* __restrict__ whh,
                                                    const float* __restrict__ bhh,
                                                    u16* __restrict__ mbx,
                                                    float* __restrict__ out,
                                                    const u16* __restrict__ emb16,
                                                    int eb16) {
  extern __shared__ u16 smem[];
  u16* xq = smem;                                   // [1024][16] token ids, 32KB
  float (*red)[4][16][68] = (float (*)[4][16][68])(smem + S_LEN * 16);  // 34KB
  const int tid = threadIdx.x;
  const int lane = tid & 63, w = tid >> 6;
  const int l15 = lane & 15, l4 = lane >> 4;
  const int g = blockIdx.x & 15;
  const int jt = blockIdx.x >> 4;

  // ---- prologue: weights into registers ----
  short8v Wf[4][8];
  #pragma unroll
  for (int jj = 0; jj < 4; jj++)
    #pragma unroll
    for (int kq = 0; kq < 8; kq++) {
      const float* s = whh + (size_t)(jt * 64 + jj * 16 + l15) * HIDDEN
                       + w * 256 + kq * 32 + l4 * 8;
      Wf[jj][kq] = cvt8(*(const float4v*)s, *(const float4v*)(s + 4));
    }
  short8v Wihf[4][4];
  #pragma unroll
  for (int jj = 0; jj < 4; jj++)
    #pragma unroll
    for (int kk = 0; kk < 4; kk++) {
      const float* s = wih + (size_t)(jt * 64 + jj * 16 + l15) * EMBED
                       + w * 128 + kk * 32 + l4 * 8;
      Wihf[jj][kk] = cvt8(*(const float4v*)s, *(const float4v*)(s + 4));
    }
  for (int i = tid; i < S_LEN * 16; i += 256)
    xq[i] = (u16)xseq[(i >> 4) * BATCH + g * 16 + (i & 15)];
  const int trow = w * 4 + (lane >> 4);
  const int tc4 = (lane & 15) * 4;
  float bsum[4];
  #pragma unroll
  for (int i = 0; i < 4; i++)
    bsum[i] = bhh[jt * 64 + tc4 + i] + bih[jt * 64 + tc4 + i];
  const int w_t = jt >> 2;
  const int l_t = trow + 16 * ((tc4 >> 3) & 3);
  const int u_idx = (jt & 3) * 4 + ((tc4 >> 5) & 1) * 2 + ((tc4 >> 2) & 1);
  const int moff = (((g * 4 + w_t) * 64 + l_t) * 16 + u_idx) * 16;
  const int cbase = ((g * 4 + w) * 64 + lane) * 128;
  __syncthreads();  // xq ready

  // ---- xp-partials for t=0 ----
  float4v xacc[4] = {};
  if (eb16) {
    const u16* er0 = emb16 + (size_t)xq[l15] * EMBED + w * 128 + l4 * 8;
    #pragma unroll
    for (int kk = 0; kk < 4; kk++) {
      short8v af = *(const short8v*)(er0 + kk * 32);
      #pragma unroll
      for (int jj = 0; jj < 4; jj++)
        xacc[jj] = __builtin_amdgcn_mfma_f32_16x16x32_bf16(af, Wihf[jj][kk], xacc[jj], 0, 0, 0);
    }
  } else {
    const float* er0 = emb + (size_t)xq[l15] * EMBED + w * 128 + l4 * 8;
    #pragma unroll
    for (int kk = 0; kk < 4; kk++) {
      short8v af = cvt8(*(const float4v*)(er0 + kk * 32),
                        *(const float4v*)(er0 + kk * 32 + 4));
      #pragma unroll
      for (int jj = 0; jj < 4; jj++)
        xacc[jj] = __builtin_amdgcn_mfma_f32_16x16x32_bf16(af, Wihf[jj][kk], xacc[jj], 0, 0, 0);
    }
  }

  for (int t = 0; t < S_LEN; t++) {
    float* outt = out + (size_t)t * BH;
    float4v accp[4] = {xacc[0], xacc[1], xacc[2], xacc[3]};
    // e-loads for t+1 (plain cached; retired by the poll's vmcnt(0))
    int tn = (t + 1 < S_LEN) ? (t + 1) : t;
    short8v ebf[4];
    float4v e[8];
    if (eb16) {
      const u16* er = emb16 + (size_t)xq[tn * 16 + l15] * EMBED + w * 128 + l4 * 8;
      #pragma unroll
      for (int kk = 0; kk < 4; kk++)
        ebf[kk] = *(const short8v*)(er + kk * 32);
    } else {
      const float* er = emb + (size_t)xq[tn * 16 + l15] * EMBED + w * 128 + l4 * 8;
      #pragma unroll
      for (int kk = 0; kk < 4; kk++) {
        e[2 * kk]     = *(const float4v*)(er + kk * 32);
        e[2 * kk + 1] = *(const float4v*)(er + kk * 32 + 4);
      }
    }
    if (t > 0) {
      const u16* pb = mbx + (size_t)(t & 1) * (MB_SLOT / 2) + cbase;
      const u32 tt = (u32)t;
      uint4v u0,u1,u2,u3,u4,u5,u6,u7,u8,u9,u10,u11,u12,u13,u14,u15;
      // phase 1: speculative full load (data arrives WITH the tag check)
      LOAD_UNITS(pb);
      bool ok = (u0[0]==tt) & (u1[0]==tt) & (u2[0]==tt) & (u3[0]==tt) &
                (u4[0]==tt) & (u5[0]==tt) & (u6[0]==tt) & (u7[0]==tt) &
                (u8[0]==tt) & (u9[0]==tt) & (u10[0]==tt) & (u11[0]==tt) &
                (u12[0]==tt) & (u13[0]==tt) & (u14[0]==tt) & (u15[0]==tt);
      if (!ok) {
        // phase 2: cheap tag-only spin (64B/lane/iter), then one reload
        u32 g0,g1,g2,g3,g4,g5,g6,g7,g8,g9,g10,g11,g12,g13,g14,g15;
        bool tok;
        do {
          LOAD_TAGS(pb);
          tok = (g0==tt) & (g1==tt) & (g2==tt) & (g3==tt) &
                (g4==tt) & (g5==tt) & (g6==tt) & (g7==tt) &
                (g8==tt) & (g9==tt) & (g10==tt) & (g11==tt) &
                (g12==tt) & (g13==tt) & (g14==tt) & (g15==tt);
        } while (!tok);
        LOAD_UNITS(pb);
      }
      short8v afr[8];
      afr[0] = mkfrag(u0, u1);   afr[1] = mkfrag(u2, u3);
      afr[2] = mkfrag(u4, u5);   afr[3] = mkfrag(u6, u7);
      afr[4] = mkfrag(u8, u9);   afr[5] = mkfrag(u10, u11);
      afr[6] = mkfrag(u12, u13); afr[7] = mkfrag(u14, u15);
      #pragma unroll
      for (int kq = 0; kq < 8; kq++)
        #pragma unroll
        for (int jj = 0; jj < 4; jj++)
          accp[jj] = __builtin_amdgcn_mfma_f32_16x16x32_bf16(afr[kq], Wf[jj][kq], accp[jj], 0, 0, 0);
    }
    // partials -> red[t&1]; ONE barrier (orders all polls before unit stores)
    const int p = t & 1;
    #pragma unroll
    for (int jj = 0; jj < 4; jj++)
      #pragma unroll
      for (int q = 0; q < 4; q++)
        red[p][w][l4 * 4 + q][jj * 16 + l15] = accp[jj][q];
    __syncthreads();
    float4v r0 = *(const float4v*)&red[p][0][trow][tc4];
    float4v r1 = *(const float4v*)&red[p][1][trow][tc4];
    float4v r2 = *(const float4v*)&red[p][2][trow][tc4];
    float4v r3 = *(const float4v*)&red[p][3][trow][tc4];
    float th[4];
    #pragma unroll
    for (int i = 0; i < 4; i++) {
      float s = r0[i] + r1[i] + r2[i] + r3[i] + bsum[i];
      float ex = __expf(-2.0f * fabsf(s));
      float v = (1.0f - ex) / (1.0f + ex);
      th[i] = copysignf(v, s);
    }
    // mailbox unit store {tag t+1, 4 bf16, pad}; fire&forget (no drain/flag)
    uint4v mval;
    mval[0] = (u32)(t + 1);
    mval[1] = (u32)f2bf(th[0]) | ((u32)f2bf(th[1]) << 16);
    mval[2] = (u32)f2bf(th[2]) | ((u32)f2bf(th[3]) << 16);
    mval[3] = 0u;
    cohstore16u(mbx, ((t + 1) & 1) * MB_SLOT + moff, mval);
    // fp32 out store (nobody reads it cross-block)
    float4v o = {th[0], th[1], th[2], th[3]};
    *(float4v*)(outt + (size_t)(g * 16 + trow) * HIDDEN + jt * 64 + tc4) = o;
    // xp-MFMA for t+1 (overlaps next step's speculative load)
    float4v xn[4] = {};
    #pragma unroll
    for (int kk = 0; kk < 4; kk++) {
      short8v af = eb16 ? ebf[kk] : cvt8(e[2 * kk], e[2 * kk + 1]);
      #pragma unroll
      for (int jj = 0; jj < 4; jj++)
        xn[jj] = __builtin_amdgcn_mfma_f32_16x16x32_bf16(af, Wihf[jj][kk], xn[jj], 0, 0, 0);
    }
    xacc[0] = xn[0]; xacc[1] = xn[1]; xacc[2] = xn[2]; xacc[3] = xn[3];
  }
}

extern "C" void kernel_launch(void* const* d_in, const int* in_sizes, int n_in,
                              void* d_out, int out_size, void* d_ws, size_t ws_size,
                              hipStream_t stream) {
  const int* xseq   = (const int*)d_in[0];
  const float* emb  = (const float*)d_in[1];
  const float* wih  = (const float*)d_in[2];
  const float* bih  = (const float*)d_in[3];
  const float* whh  = (const float*)d_in[4];
  const float* bhh  = (const float*)d_in[5];
  float* out = (float*)d_out;
  char* ws = (char*)d_ws;
  u16* mbx   = (u16*)ws;                      // 2,097,152 B (2 mailbox slots)
  u16* emb16 = (u16*)(ws + 2097152);          // 32,768,000 B (bf16 emb)

  const size_t need = 2097152u + (size_t)VOCAB * EMBED * 2u;
  const int do_emb = (ws_size >= need) ? 1 : 0;
  const int prep_items = 131072 + (do_emb ? (VOCAB * EMBED) / 8 : 0);

  prep_kernel<<<(prep_items + 255) / 256, 256, 0, stream>>>(mbx, emb, emb16, do_emb);
  (void)hipFuncSetAttribute((const void*)rnn_fused,
                            hipFuncAttributeMaxDynamicSharedMemorySize, 67584);
  rnn_fused<<<256, 256, 67584, stream>>>(xseq, emb, wih, bih, whh, bhh,
                                         mbx, out, emb16, do_emb);
}

// Round 16
// 3248.576 us; speedup vs baseline: 1.7197x; 1.7120x over previous
//
#include <hip/hip_runtime.h>
#include <hip/hip_bf16.h>

typedef unsigned short u16;
typedef unsigned int u32;
typedef __attribute__((ext_vector_type(8))) short short8v;      // MFMA bf16 frag (4 VGPR)
typedef __attribute__((ext_vector_type(8))) unsigned short ushort8v;
typedef __attribute__((ext_vector_type(4))) float float4v;
typedef __attribute__((ext_vector_type(4))) unsigned int uint4v;
typedef __attribute__((ext_vector_type(2))) unsigned int uint2v;

#define S_LEN 1024
#define BATCH 256
#define VOCAB 32000
#define EMBED 512
#define HIDDEN 1024
#define BH (BATCH * HIDDEN)
#define FLAG_STRIDE 32   // u32s (128B) per flag: distinct cache lines

__device__ inline u16 f2bf(float f) {
  return __builtin_bit_cast(u16, __float2bfloat16(f));  // RNE
}

// Coherent (sc0|sc1 = cpol 17: L2-bypass, L3 coherent point) ops. PROVEN path.
__device__ inline short8v cohload16(const u16* base, int voff) {
  __amdgpu_buffer_rsrc_t r =
      __builtin_amdgcn_make_buffer_rsrc((void*)base, (short)0, -1, 0x00020000);
  uint4v d = __builtin_amdgcn_raw_buffer_load_b128(r, voff, 0, 17);
  return __builtin_bit_cast(short8v, d);
}
__device__ inline void cohstore8(u16* base, int voff, uint2v v) {
  __amdgpu_buffer_rsrc_t r =
      __builtin_amdgcn_make_buffer_rsrc((void*)base, (short)0, -1, 0x00020000);
  __builtin_amdgcn_raw_buffer_store_b64(v, r, voff, 0, 17);
}

__device__ inline short8v cvt8(float4v a, float4v b) {
  ushort8v v;
  v[0]=f2bf(a[0]); v[1]=f2bf(a[1]); v[2]=f2bf(a[2]); v[3]=f2bf(a[3]);
  v[4]=f2bf(b[0]); v[5]=f2bf(b[1]); v[6]=f2bf(b[2]); v[7]=f2bf(b[3]);
  return __builtin_bit_cast(short8v, v);
}

// ---------------- prep: zero hbuf+flags; emb -> bf16 ----------------
__global__ __launch_bounds__(256) void prep_kernel(u16* __restrict__ ws16,
                                                   const float* __restrict__ emb,
                                                   u16* __restrict__ emb16,
                                                   int do_emb) {
  int i = blockIdx.x * 256 + threadIdx.x;
  const int NZ = 73728;                 // (1MB hbuf + 128KB flags) / 16B
  if (i < NZ) {
    ushort8v z = {0,0,0,0,0,0,0,0};
    *(ushort8v*)(ws16 + (size_t)i * 8) = z;
  } else if (do_emb) {
    int j = i - NZ;                     // 2,048,000 chunks of 8 floats
    if (j < (VOCAB * EMBED) / 8) {
      const float* s = emb + (size_t)j * 8;
      *(ushort8v*)(emb16 + (size_t)j * 8) = __builtin_bit_cast(
          ushort8v, cvt8(*(const float4v*)s, *(const float4v*)(s + 4)));
    }
  }
}

// ---------------- fused recurrence + input projection ----------------
// 256 persistent blocks = 16 groups (16 batch rows) x 16 col-tiles (64 cols).
// Per wave (k-split x4): W_hh quarter (128 VGPR) + W_ih quarter in registers.
// Exchange protocol (PROVEN R10/R12): cpol17 h store/load, vmcnt(0) drain,
// value flags (agent relaxed). R16 delta: 4-deep pipelined poll (detect at
// ~RTT/4 granularity). Stray in-flight polls are SAFE because their dest
// VGPRs are kept live until the end of the step body (>= 2 RTT later) via an
// empty asm use -- R15's crash was register reuse before stray completion.
__global__ __launch_bounds__(256, 1) void rnn_fused(const int* __restrict__ xseq,
                                                    const float* __restrict__ emb,
                                                    const float* __restrict__ wih,
                                                    const float* __restrict__ bih,
                                                    const float* __restrict__ whh,
                                                    const float* __restrict__ bhh,
                                                    u16* __restrict__ hbuf,
                                                    float* __restrict__ out,
                                                    u32* __restrict__ flag,
                                                    const u16* __restrict__ emb16,
                                                    int eb16) {
  extern __shared__ u16 smem[];
  u16* xq = smem;                                   // [1024][16] token ids, 32KB
  float (*red)[4][16][68] = (float (*)[4][16][68])(smem + S_LEN * 16);  // 34KB
  const int tid = threadIdx.x;
  const int lane = tid & 63, w = tid >> 6;
  const int l15 = lane & 15, l4 = lane >> 4;
  const int g = blockIdx.x & 15;             // batch rows [g*16, g*16+16)
  const int jt = blockIdx.x >> 4;            // hidden cols [jt*64, jt*64+64)

  // ---- prologue: weights into registers ----
  short8v Wf[4][8];   // W_hh[col jt*64+jj*16+l15][k = w*256+kq*32+l4*8 ..+8]
  #pragma unroll
  for (int jj = 0; jj < 4; jj++)
    #pragma unroll
    for (int kq = 0; kq < 8; kq++) {
      const float* s = whh + (size_t)(jt * 64 + jj * 16 + l15) * HIDDEN
                       + w * 256 + kq * 32 + l4 * 8;
      Wf[jj][kq] = cvt8(*(const float4v*)s, *(const float4v*)(s + 4));
    }
  short8v Wihf[4][4]; // W_ih[col][k = w*128+kk*32+l4*8 ..+8]
  #pragma unroll
  for (int jj = 0; jj < 4; jj++)
    #pragma unroll
    for (int kk = 0; kk < 4; kk++) {
      const float* s = wih + (size_t)(jt * 64 + jj * 16 + l15) * EMBED
                       + w * 128 + kk * 32 + l4 * 8;
      Wihf[jj][kk] = cvt8(*(const float4v*)s, *(const float4v*)(s + 4));
    }
  for (int i = tid; i < S_LEN * 16; i += 256)
    xq[i] = (u16)xseq[(i >> 4) * BATCH + g * 16 + (i & 15)];
  const int trow = w * 4 + (lane >> 4);
  const int tc4 = (lane & 15) * 4;
  float bsum[4];
  #pragma unroll
  for (int i = 0; i < 4; i++)
    bsum[i] = bhh[jt * 64 + tc4 + i] + bih[jt * 64 + tc4 + i];
  const int aoff = ((g * 16 + l15) * HIDDEN + w * 256 + l4 * 8) * 2;
  const int hoff = ((g * 16 + trow) * HIDDEN + jt * 64 + tc4) * 2;
  __syncthreads();  // xq ready

  // ---- xp-partials for t=0 ----
  float4v xacc[4] = {};
  if (eb16) {
    const u16* er0 = emb16 + (size_t)xq[l15] * EMBED + w * 128 + l4 * 8;
    #pragma unroll
    for (int kk = 0; kk < 4; kk++) {
      short8v af = *(const short8v*)(er0 + kk * 32);
      #pragma unroll
      for (int jj = 0; jj < 4; jj++)
        xacc[jj] = __builtin_amdgcn_mfma_f32_16x16x32_bf16(af, Wihf[jj][kk], xacc[jj], 0, 0, 0);
    }
  } else {
    const float* er0 = emb + (size_t)xq[l15] * EMBED + w * 128 + l4 * 8;
    #pragma unroll
    for (int kk = 0; kk < 4; kk++) {
      short8v af = cvt8(*(const float4v*)(er0 + kk * 32),
                        *(const float4v*)(er0 + kk * 32 + 4));
      #pragma unroll
      for (int jj = 0; jj < 4; jj++)
        xacc[jj] = __builtin_amdgcn_mfma_f32_16x16x32_bf16(af, Wihf[jj][kk], xacc[jj], 0, 0, 0);
    }
  }

  for (int t = 0; t < S_LEN; t++) {
    const int p = t & 1;
    float* outt = out + (size_t)t * BH;
    float4v accp[4] = {xacc[0], xacc[1], xacc[2], xacc[3]};
    // poll registers: live for the WHOLE step so stray in-flight poll loads
    // land in reserved registers (see keep-alive at the bottom of the loop).
    u32 pa = 0, pb = 0, pc = 0, pd = 0;
    // per-wave poll: wave w needs producer blocks jt' = w*4..w*4+3, waves 0..3
    if (t > 0) {
      if (lane < 16) {
        const u32* f = flag +
            ((size_t)(g * 16 + w * 4 + (lane >> 2)) * 4 + (lane & 3)) * FLAG_STRIDE;
        const u32 tt = (u32)t;
        // 4-deep rotating spin: check the oldest outstanding poll each slot.
        asm volatile(
          "global_load_dword %[a], %[p], off sc0 sc1\n\t"
          "global_load_dword %[b], %[p], off sc0 sc1\n\t"
          "global_load_dword %[c], %[p], off sc0 sc1\n\t"
          "1:\n\t"
          "global_load_dword %[d], %[p], off sc0 sc1\n\t"
          "s_waitcnt vmcnt(3)\n\t"
          "v_cmp_lt_u32 vcc, %[a], %[t]\n\t"
          "s_cbranch_vccz 9f\n\t"
          "global_load_dword %[a], %[p], off sc0 sc1\n\t"
          "s_waitcnt vmcnt(3)\n\t"
          "v_cmp_lt_u32 vcc, %[b], %[t]\n\t"
          "s_cbranch_vccz 9f\n\t"
          "global_load_dword %[b], %[p], off sc0 sc1\n\t"
          "s_waitcnt vmcnt(3)\n\t"
          "v_cmp_lt_u32 vcc, %[c], %[t]\n\t"
          "s_cbranch_vccz 9f\n\t"
          "global_load_dword %[c], %[p], off sc0 sc1\n\t"
          "s_waitcnt vmcnt(3)\n\t"
          "v_cmp_lt_u32 vcc, %[d], %[t]\n\t"
          "s_cbranch_vccnz 1b\n\t"
          "9:"
          : [a]"+v"(pa), [b]"+v"(pb), [c]"+v"(pc), [d]"+v"(pd)
          : [p]"v"(f), [t]"v"(tt)
          : "vcc", "memory");
      }
    }
    __builtin_amdgcn_sched_barrier(0);  // h-loads strictly after the poll
    const u16* hp = hbuf + (size_t)p * BH;
    short8v a[8];
    #pragma unroll
    for (int kq = 0; kq < 8; kq++)
      a[kq] = cohload16(hp, aoff + kq * 64);
    __builtin_amdgcn_sched_barrier(0);  // e-loads strictly after h-loads
    // e-loads for t+1 (h-MFMA waits only its h-frags; these drain before flag)
    int tn = (t + 1 < S_LEN) ? (t + 1) : t;
    short8v ebf[4];
    float4v e[8];
    if (eb16) {
      const u16* er = emb16 + (size_t)xq[tn * 16 + l15] * EMBED + w * 128 + l4 * 8;
      #pragma unroll
      for (int kk = 0; kk < 4; kk++)
        ebf[kk] = *(const short8v*)(er + kk * 32);
    } else {
      const float* er = emb + (size_t)xq[tn * 16 + l15] * EMBED + w * 128 + l4 * 8;
      #pragma unroll
      for (int kk = 0; kk < 4; kk++) {
        e[2 * kk]     = *(const float4v*)(er + kk * 32);
        e[2 * kk + 1] = *(const float4v*)(er + kk * 32 + 4);
      }
    }
    // h-MFMA
    #pragma unroll
    for (int kq = 0; kq < 8; kq++)
      #pragma unroll
      for (int jj = 0; jj < 4; jj++)
        accp[jj] = __builtin_amdgcn_mfma_f32_16x16x32_bf16(a[kq], Wf[jj][kq], accp[jj], 0, 0, 0);
    // partials -> red[t&1]  (double-buffered: ONE barrier per step)
    #pragma unroll
    for (int jj = 0; jj < 4; jj++)
      #pragma unroll
      for (int q = 0; q < 4; q++)
        red[p][w][l4 * 4 + q][jj * 16 + l15] = accp[jj][q];
    __syncthreads();
    float4v r0 = *(const float4v*)&red[p][0][trow][tc4];
    float4v r1 = *(const float4v*)&red[p][1][trow][tc4];
    float4v r2 = *(const float4v*)&red[p][2][trow][tc4];
    float4v r3 = *(const float4v*)&red[p][3][trow][tc4];
    float th[4];
    #pragma unroll
    for (int i = 0; i < 4; i++) {
      float s = r0[i] + r1[i] + r2[i] + r3[i] + bsum[i];
      float ex = __expf(-2.0f * fabsf(s));
      float v = (1.0f - ex) / (1.0f + ex);
      th[i] = copysignf(v, s);
    }
    // bf16 h store (exchange) -> drain -> flag; fp32 out AFTER publish
    uint2v hv;
    hv[0] = (u32)f2bf(th[0]) | ((u32)f2bf(th[1]) << 16);
    hv[1] = (u32)f2bf(th[2]) | ((u32)f2bf(th[3]) << 16);
    u16* hq = hbuf + (size_t)(p ^ 1) * BH;
    cohstore8(hq, hoff, hv);
    asm volatile("s_waitcnt vmcnt(0)" ::: "memory");  // h at coherent point
    if (lane == 0)
      __hip_atomic_store(flag + ((size_t)(g * 16 + jt) * 4 + w) * FLAG_STRIDE,
                         (u32)(t + 1), __ATOMIC_RELAXED, __HIP_MEMORY_SCOPE_AGENT);
    float4v o = {th[0], th[1], th[2], th[3]};
    *(float4v*)(outt + (size_t)(g * 16 + trow) * HIDDEN + jt * 64 + tc4) = o;
    // xp-MFMA for t+1 (e already resident; overlaps next poll wait)
    float4v xn[4] = {};
    #pragma unroll
    for (int kk = 0; kk < 4; kk++) {
      short8v af = eb16 ? ebf[kk] : cvt8(e[2 * kk], e[2 * kk + 1]);
      #pragma unroll
      for (int jj = 0; jj < 4; jj++)
        xn[jj] = __builtin_amdgcn_mfma_f32_16x16x32_bf16(af, Wihf[jj][kk], xn[jj], 0, 0, 0);
    }
    xacc[0] = xn[0]; xacc[1] = xn[1]; xacc[2] = xn[2]; xacc[3] = xn[3];
    // keep-alive: reserve pa..pd until here (~2 RTT after poll exit) so any
    // stray in-flight poll load lands in a still-reserved register.
    asm volatile("" : "+v"(pa), "+v"(pb), "+v"(pc), "+v"(pd));
  }
}

extern "C" void kernel_launch(void* const* d_in, const int* in_sizes, int n_in,
                              void* d_out, int out_size, void* d_ws, size_t ws_size,
                              hipStream_t stream) {
  const int* xseq   = (const int*)d_in[0];
  const float* emb  = (const float*)d_in[1];
  const float* wih  = (const float*)d_in[2];
  const float* bih  = (const float*)d_in[3];
  const float* whh  = (const float*)d_in[4];
  const float* bhh  = (const float*)d_in[5];
  float* out = (float*)d_out;
  char* ws = (char*)d_ws;
  u16* hbuf  = (u16*)ws;                      // 1,048,576 B
  u32* flag  = (u32*)(ws + 1048576);          // 131,072 B (1024 flags, 128B stride)
  u16* emb16 = (u16*)(ws + 1179648);          // 32,768,000 B (bf16 emb), if it fits

  const size_t need = 1179648u + (size_t)VOCAB * EMBED * 2u;
  const int do_emb = (ws_size >= need) ? 1 : 0;
  const int prep_items = 73728 + (do_emb ? (VOCAB * EMBED) / 8 : 0);

  prep_kernel<<<(prep_items + 255) / 256, 256, 0, stream>>>((u16*)ws, emb, emb16, do_emb);
  (void)hipFuncSetAttribute((const void*)rnn_fused,
                            hipFuncAttributeMaxDynamicSharedMemorySize, 67584);
  rnn_fused<<<256, 256, 67584, stream>>>(xseq, emb, wih, bih, whh, bhh,
                                         hbuf, out, flag, emb16, do_emb);
}